// Round 7
// baseline (221.964 us; speedup 1.0000x reference)
//
#include <hip/hip_runtime.h>
#include <stdint.h>
#include <stddef.h>

// T=2048, B=4, E=1024, H=16, HD=64, N-heads = B*H = 64.
// qkv reshape: f in [0,3072) -> head hq = f/192, s3 = (f/64)%3, d = f%64, n = b*16+hq.
// Layouts: Qb,Kb,Vb = [n][t][d] bf16 ; VTb = [n][d][t] bf16 (separate transpose kernel).

typedef __attribute__((ext_vector_type(8))) short bf16x8;
typedef __attribute__((ext_vector_type(4))) float f32x4;
typedef __attribute__((ext_vector_type(4))) unsigned int u32x4;

#define MFMA16(a, b, c) __builtin_amdgcn_mfma_f32_16x16x32_bf16((a), (b), (c), 0, 0, 0)

__device__ __forceinline__ unsigned short f2bf(float f) {
  unsigned u = __builtin_bit_cast(unsigned, f);
  u += 0x7fffu + ((u >> 16) & 1u);   // RNE
  return (unsigned short)(u >> 16);
}

__device__ __forceinline__ float fast_exp2(float x) {
#if __has_builtin(__builtin_amdgcn_exp2f)
  return __builtin_amdgcn_exp2f(x);
#else
  return exp2f(x);
#endif
}

__device__ __forceinline__ unsigned cvtpk(float lo, float hi) {
  unsigned r;
  asm volatile("v_cvt_pk_bf16_f32 %0, %1, %2" : "=v"(r) : "v"(lo), "v"(hi));
  return r;
}

__device__ __forceinline__ void gload_lds16(const void* g, void* l) {
  __builtin_amdgcn_global_load_lds((const __attribute__((address_space(1))) void*)g,
                                   (__attribute__((address_space(3))) void*)l,
                                   16, 0, 0);
}

// ---------------- fp32 -> bf16 convert ----------------
__global__ __launch_bounds__(256) void k_cvt(const float* __restrict__ src,
                                             unsigned short* __restrict__ dst, int n4) {
  int i = blockIdx.x * 256 + threadIdx.x;
  if (i >= n4) return;
  const float4 v = ((const float4*)src)[i];
  ushort4 o;
  o.x = f2bf(v.x); o.y = f2bf(v.y); o.z = f2bf(v.z); o.w = f2bf(v.w);
  ((ushort4*)dst)[i] = o;
}

// ---------------- GEMM1: X[8192][1024] x W1t[3072][1024] -> scatter Q/K/V ----------------
__global__ __launch_bounds__(256, 2) void k_gemm_qkv(
    const unsigned short* __restrict__ A,
    const unsigned short* __restrict__ Bt,
    unsigned short* __restrict__ Qb,        // [64][2048][64]
    unsigned short* __restrict__ Kb,        // [64][2048][64]
    unsigned short* __restrict__ Vb) {      // [64][2048][64]
  constexpr int K = 1024;
  __shared__ __align__(16) unsigned short As[128 * 32];
  __shared__ __align__(16) unsigned short Bs[128 * 32];
  const int tid = threadIdx.x;
  const int l = tid & 63, w = tid >> 6;
  const int lr = l & 15, lg = l >> 4;
  const int bm = blockIdx.x, bn = blockIdx.y;
  const int wr = (w >> 1) * 64, wc = (w & 1) * 64;

  f32x4 acc[4][4] = {};

  const int o0 = tid * 16, o1 = tid * 16 + 4096;
  const int r0 = o0 >> 6, c0 = o0 & 63;
  const int r1 = o1 >> 6, c1 = o1 & 63;
  const char* gA0 = (const char*)A + (size_t)(bm * 128 + r0) * (K * 2) + c0;
  const char* gA1 = (const char*)A + (size_t)(bm * 128 + r1) * (K * 2) + c1;
  const char* gB0 = (const char*)Bt + (size_t)(bn * 128 + r0) * (K * 2) + c0;
  const char* gB1 = (const char*)Bt + (size_t)(bn * 128 + r1) * (K * 2) + c1;
  char* lA0 = (char*)As + o0;
  char* lA1 = (char*)As + o1;
  char* lB0 = (char*)Bs + o0;
  char* lB1 = (char*)Bs + o1;

  for (int kt = 0; kt < K / 32; ++kt) {
    const int kb = kt * 64;
    gload_lds16(gA0 + kb, lA0);
    gload_lds16(gA1 + kb, lA1);
    gload_lds16(gB0 + kb, lB0);
    gload_lds16(gB1 + kb, lB1);
    __syncthreads();
    bf16x8 af[4], bfr[4];
#pragma unroll
    for (int mf = 0; mf < 4; ++mf)
      af[mf] = *(const bf16x8*)&As[(wr + mf * 16 + lr) * 32 + lg * 8];
#pragma unroll
    for (int nf = 0; nf < 4; ++nf)
      bfr[nf] = *(const bf16x8*)&Bs[(wc + nf * 16 + lr) * 32 + lg * 8];
#pragma unroll
    for (int mf = 0; mf < 4; ++mf)
#pragma unroll
      for (int nf = 0; nf < 4; ++nf)
        acc[mf][nf] = MFMA16(af[mf], bfr[nf], acc[mf][nf]);
    __syncthreads();
  }

  // D layout: col = lane&15, row = (lane>>4)*4 + i. Coalesced [n][t][d] for Q,K,V.
#pragma unroll
  for (int nf = 0; nf < 4; ++nf) {
    const int f = bn * 128 + wc + nf * 16 + lr;
    const int hq = f / 192;
    const int s3 = (f >> 6) % 3;
    const int d = f & 63;
    unsigned short* dst = (s3 == 0) ? Qb : (s3 == 1) ? Kb : Vb;
    // fold SCALE*log2(e) into Q so softmax is a bare exp2
    const float qscale = (s3 == 0) ? 0.18033688011112042f : 1.0f;
#pragma unroll
    for (int mf = 0; mf < 4; ++mf) {
#pragma unroll
      for (int i = 0; i < 4; ++i) {
        const int r = bm * 128 + wr + mf * 16 + lg * 4 + i;
        const int t = r >> 2, bb2 = r & 3;
        const int nIdx = bb2 * 16 + hq;
        dst[((size_t)nIdx * 2048 + t) * 64 + d] = f2bf(acc[mf][nf][i] * qscale);
      }
    }
  }
}

// ---------------- V transpose: [n][t][d] -> [n][d][t] ----------------
__global__ __launch_bounds__(256) void k_vtrans(const unsigned short* __restrict__ V,
                                                unsigned short* __restrict__ VT) {
  __shared__ unsigned short tile[64][66];
  const int tid = threadIdx.x;
  const int n = blockIdx.y, t0 = blockIdx.x * 64;
  const int r = tid >> 2, c0 = (tid & 3) * 16;
  const unsigned short* src = V + ((size_t)(n * 2048 + t0 + r) * 64 + c0);
  bf16x8 a = *(const bf16x8*)src;
  bf16x8 b = *(const bf16x8*)(src + 8);
#pragma unroll
  for (int j = 0; j < 8; ++j) tile[r][c0 + j] = (unsigned short)a[j];
#pragma unroll
  for (int j = 0; j < 8; ++j) tile[r][c0 + 8 + j] = (unsigned short)b[j];
  __syncthreads();
  const int d = tid >> 2, u0 = (tid & 3) * 16;
  bf16x8 oA, oB;
#pragma unroll
  for (int j = 0; j < 8; ++j) oA[j] = (short)tile[u0 + j][d];
#pragma unroll
  for (int j = 0; j < 8; ++j) oB[j] = (short)tile[u0 + 8 + j][d];
  unsigned short* dst = VT + ((size_t)(n * 64 + d) * 2048 + t0 + u0);
  *(bf16x8*)dst = oA;
  *(bf16x8*)(dst + 8) = oB;
}

// ---------------- flash attention: KVBLK=128, K-row-permuted QK^T (zero-shuffle PV) ----------------
__global__ __launch_bounds__(256, 2) void k_attn(
    const unsigned short* __restrict__ Qb, const unsigned short* __restrict__ Kb,
    const unsigned short* __restrict__ VTb, unsigned short* __restrict__ Cx) {
  // K: [128 s][64 d] rows of 128B, swizzle g_K(row) = (row&3)|(((row>>3)&1)<<2), col ^= g_K<<4
  // V: [64 d][128 s] rows of 256B, swizzle (row&7)<<4
  __shared__ __align__(16) unsigned short Ks[2][128 * 64];
  __shared__ __align__(16) unsigned short Vt[2][64 * 128];

  const int tid = threadIdx.x;
  const int l = tid & 63, w = tid >> 6;
  const int lq = l & 15, lg = l >> 4;
  const int n = blockIdx.x, qt = blockIdx.y;   // x = head -> same-head blocks on one XCD

  const unsigned short* Qh = Qb + (size_t)n * (2048 * 64);
  const unsigned short* Kh = Kb + (size_t)n * (2048 * 64);
  const unsigned short* Vh = VTb + (size_t)n * (64 * 2048);

  // Q fragments (B-operand of swapped QK^T): q = qt*256 + w*64 + qf*16 + lq
  bf16x8 aq[4][2];
#pragma unroll
  for (int qf = 0; qf < 4; ++qf)
#pragma unroll
    for (int kd = 0; kd < 2; ++kd)
      aq[qf][kd] = *(const bf16x8*)&Qh[(size_t)(qt * 256 + w * 64 + qf * 16 + lq) * 64 +
                                       kd * 32 + lg * 8];

  f32x4 o[4][4] = {};       // O^T acc: [df][qf]; lane: q = lq, d = df*16 + lg*4 + i
  float lsum[4] = {0.f, 0.f, 0.f, 0.f};

  char* Ksl = (char*)&Ks[0][0];
  char* Vtl = (char*)&Vt[0][0];

  // per-lane constant addressing for the permuted K read and V read
  const int swzK = (((lq & 3) | (((lq >> 2) & 1) << 2)) << 4);
  const int colK0 = (lg * 16) ^ swzK;
  const int colK1 = (64 + lg * 16) ^ swzK;
  const int rowbase = (lq >> 2) * 8 + (lq & 3);   // sigma: A-row m=lq holds K key rowbase(+4)
  const int swzV = (lq & 7) << 4;

  // stage 128 keys: K 16KB + V^T 16KB (8 loads/thread)
  auto STAGE = [&](int buf, int st) {
    const int s0 = st * 128;
#pragma unroll
    for (int it = 0; it < 4; ++it) {
      const int off = (it * 256 + tid) * 16;
      const int row = off >> 7;                 // 0..127
      const int col = off & 127;
      const int g = (row & 3) | (((row >> 3) & 1) << 2);
      gload_lds16((const char*)Kh + ((size_t)(s0 + row) << 7) + (col ^ (g << 4)),
                  Ksl + buf * 16384 + off);
    }
#pragma unroll
    for (int it = 0; it < 4; ++it) {
      const int off = (it * 256 + tid) * 16;
      const int row = off >> 8;                 // 0..63
      const int col = off & 255;
      gload_lds16((const char*)Vh + ((size_t)row << 12) + (s0 << 1) + (col ^ ((row & 7) << 4)),
                  Vtl + buf * 16384 + off);
    }
  };

  STAGE(0, 0);
  asm volatile("s_waitcnt vmcnt(0)" ::: "memory");
  __builtin_amdgcn_s_barrier();

#pragma unroll 2
  for (int st = 0; st < 16; ++st) {
    if (st + 1 < 16) STAGE((st + 1) & 1, st + 1);   // issue next-tile loads early

    const char* Kc = Ksl + (st & 1) * 16384;
    const char* Vc = Vtl + (st & 1) * 16384;

    __builtin_amdgcn_s_setprio(1);
#pragma unroll
    for (int kb = 0; kb < 4; ++kb) {
      // permuted K fragments: A-row m=lq holds key kb*32 + rowbase + f*4
      bf16x8 kf[2][2];
#pragma unroll
      for (int f = 0; f < 2; ++f) {
        const int row = kb * 32 + rowbase + f * 4;
        kf[f][0] = *(const bf16x8*)(Kc + row * 128 + colK0);
        kf[f][1] = *(const bf16x8*)(Kc + row * 128 + colK1);
      }

      // QK^T + exp2 + pack: D-output IS the PV B-fragment (s = lg*8 + j), zero shuffles
      bf16x8 pq[4];
#pragma unroll
      for (int qf = 0; qf < 4; ++qf) {
        f32x4 s1 = {0.f, 0.f, 0.f, 0.f};
        f32x4 s2 = {0.f, 0.f, 0.f, 0.f};
        s1 = MFMA16(kf[0][0], aq[qf][0], s1);
        s1 = MFMA16(kf[0][1], aq[qf][1], s1);
        s2 = MFMA16(kf[1][0], aq[qf][0], s2);
        s2 = MFMA16(kf[1][1], aq[qf][1], s2);
        float accs = 0.f;
#pragma unroll
        for (int i = 0; i < 4; ++i) {
          s1[i] = fast_exp2(s1[i]);
          s2[i] = fast_exp2(s2[i]);
          accs += s1[i] + s2[i];
        }
        lsum[qf] += accs;
        u32x4 t4 = {cvtpk(s1[0], s1[1]), cvtpk(s1[2], s1[3]),
                    cvtpk(s2[0], s2[1]), cvtpk(s2[2], s2[3])};
        pq[qf] = __builtin_bit_cast(bf16x8, t4);
      }

      // PV: O^T += V^T(:, s-block kb) . P^T
#pragma unroll
      for (int df = 0; df < 4; ++df) {
        const int rowd = df * 16 + lq;
        bf16x8 vf = *(const bf16x8*)(Vc + rowd * 256 + ((kb * 64 + lg * 16) ^ swzV));
#pragma unroll
        for (int qf = 0; qf < 4; ++qf)
          o[df][qf] = MFMA16(vf, pq[qf], o[df][qf]);
      }
    }
    __builtin_amdgcn_s_setprio(0);

    asm volatile("s_waitcnt vmcnt(0)" ::: "memory");
    __builtin_amdgcn_s_barrier();
  }

  // epilogue: reduce lsum over lane-groups, normalize, store
  const int bb = n >> 4, h = n & 15;
#pragma unroll
  for (int qf = 0; qf < 4; ++qf) {
    float li = lsum[qf];
    li += __shfl_xor(li, 16, 64);
    li += __shfl_xor(li, 32, 64);
    const float inv = 1.0f / li;
    const int q = qt * 256 + w * 64 + qf * 16 + lq;
#pragma unroll
    for (int df = 0; df < 4; ++df) {
      ushort4 pk;
      pk.x = f2bf(o[df][qf][0] * inv);
      pk.y = f2bf(o[df][qf][1] * inv);
      pk.z = f2bf(o[df][qf][2] * inv);
      pk.w = f2bf(o[df][qf][3] * inv);
      *(ushort4*)&Cx[(size_t)(q * 4 + bb) * 1024 + h * 64 + df * 16 + lg * 4] = pk;
    }
  }
}

// ---------------- GEMM4: ctx[8192][1024] x Wot[1024][1024] -> out fp32 ----------------
__global__ __launch_bounds__(256, 2) void k_gemm_out(
    const unsigned short* __restrict__ A,
    const unsigned short* __restrict__ Bt,
    float* __restrict__ C) {
  constexpr int K = 1024;
  __shared__ __align__(16) unsigned short As[128 * 32];
  __shared__ __align__(16) unsigned short Bs[128 * 32];
  const int tid = threadIdx.x;
  const int l = tid & 63, w = tid >> 6;
  const int lr = l & 15, lg = l >> 4;
  const int bm = blockIdx.x, bn = blockIdx.y;
  const int wr = (w >> 1) * 64, wc = (w & 1) * 64;

  f32x4 acc[4][4] = {};

  const int o0 = tid * 16, o1 = tid * 16 + 4096;
  const int r0 = o0 >> 6, c0 = o0 & 63;
  const int r1 = o1 >> 6, c1 = o1 & 63;
  const char* gA0 = (const char*)A + (size_t)(bm * 128 + r0) * (K * 2) + c0;
  const char* gA1 = (const char*)A + (size_t)(bm * 128 + r1) * (K * 2) + c1;
  const char* gB0 = (const char*)Bt + (size_t)(bn * 128 + r0) * (K * 2) + c0;
  const char* gB1 = (const char*)Bt + (size_t)(bn * 128 + r1) * (K * 2) + c1;
  char* lA0 = (char*)As + o0;
  char* lA1 = (char*)As + o1;
  char* lB0 = (char*)Bs + o0;
  char* lB1 = (char*)Bs + o1;

  for (int kt = 0; kt < K / 32; ++kt) {
    const int kb = kt * 64;
    gload_lds16(gA0 + kb, lA0);
    gload_lds16(gA1 + kb, lA1);
    gload_lds16(gB0 + kb, lB0);
    gload_lds16(gB1 + kb, lB1);
    __syncthreads();
    bf16x8 af[4], bfr[4];
#pragma unroll
    for (int mf = 0; mf < 4; ++mf)
      af[mf] = *(const bf16x8*)&As[(wr + mf * 16 + lr) * 32 + lg * 8];
#pragma unroll
    for (int nf = 0; nf < 4; ++nf)
      bfr[nf] = *(const bf16x8*)&Bs[(wc + nf * 16 + lr) * 32 + lg * 8];
#pragma unroll
    for (int mf = 0; mf < 4; ++mf)
#pragma unroll
      for (int nf = 0; nf < 4; ++nf)
        acc[mf][nf] = MFMA16(af[mf], bfr[nf], acc[mf][nf]);
    __syncthreads();
  }

#pragma unroll
  for (int mf = 0; mf < 4; ++mf)
#pragma unroll
    for (int i = 0; i < 4; ++i) {
      const int r = bm * 128 + wr + mf * 16 + lg * 4 + i;
#pragma unroll
      for (int nf = 0; nf < 4; ++nf)
        C[(size_t)r * 1024 + bn * 128 + wc + nf * 16 + lr] = acc[mf][nf][i];
    }
}

// ---------------- host launch ----------------
extern "C" void kernel_launch(void* const* d_in, const int* in_sizes, int n_in,
                              void* d_out, int out_size, void* d_ws, size_t ws_size,
                              hipStream_t stream) {
  const float* X = (const float*)d_in[0];    // (2048,4,1024)
  const float* W1 = (const float*)d_in[1];   // (3072,1024)
  const float* Wo = (const float*)d_in[2];   // (1024,1024)
  float* out = (float*)d_out;                // (2048,4,1024) fp32

  char* ws = (char*)d_ws;
  unsigned short* Xb  = (unsigned short*)(ws);              // 16 MB
  unsigned short* W1b = (unsigned short*)(ws + 16777216);   //  6 MB
  unsigned short* Wob = (unsigned short*)(ws + 23068672);   //  2 MB
  unsigned short* Qb  = (unsigned short*)(ws + 25165824);   // 16 MB
  unsigned short* Kb  = (unsigned short*)(ws + 41943040);   // 16 MB
  unsigned short* VTb = (unsigned short*)(ws + 58720256);   // 16 MB
  // Vb aliases the Cx slot: Vb is dead after k_vtrans, Cx written only by k_attn (later).
  unsigned short* Vb  = (unsigned short*)(ws + 75497472);   // 16 MB
  unsigned short* Cx  = (unsigned short*)(ws + 75497472);   // same 16 MB

  k_cvt<<<8192, 256, 0, stream>>>(X, Xb, 2097152);
  k_cvt<<<3072, 256, 0, stream>>>(W1, W1b, 786432);
  k_cvt<<<1024, 256, 0, stream>>>(Wo, Wob, 262144);
  k_gemm_qkv<<<dim3(64, 24), 256, 0, stream>>>(Xb, W1b, Qb, Kb, Vb);
  k_vtrans<<<dim3(32, 64), 256, 0, stream>>>(Vb, VTb);
  k_attn<<<dim3(64, 8), 256, 0, stream>>>(Qb, Kb, VTb, Cx);
  k_gemm_out<<<dim3(64, 8), 256, 0, stream>>>(Cx, Wob, out);
}

// Round 8
// 207.907 us; speedup vs baseline: 1.0676x; 1.0676x over previous
//
#include <hip/hip_runtime.h>
#include <stdint.h>
#include <stddef.h>

// T=2048, B=4, E=1024, H=16, HD=64, N-heads = B*H = 64.
// qkv reshape: f in [0,3072) -> head hq = f/192, s3 = (f/64)%3, d = f%64, n = b*16+hq.
// Layouts: Qb,Kb,Vb = [n][t][d] bf16 ; VTb = [n][d][t] bf16 (separate transpose kernel).

typedef __attribute__((ext_vector_type(8))) short bf16x8;
typedef __attribute__((ext_vector_type(4))) float f32x4;
typedef __attribute__((ext_vector_type(4))) unsigned int u32x4;

#define MFMA16(a, b, c) __builtin_amdgcn_mfma_f32_16x16x32_bf16((a), (b), (c), 0, 0, 0)

__device__ __forceinline__ unsigned short f2bf(float f) {
  unsigned u = __builtin_bit_cast(unsigned, f);
  u += 0x7fffu + ((u >> 16) & 1u);   // RNE
  return (unsigned short)(u >> 16);
}

__device__ __forceinline__ float fast_exp2(float x) {
#if __has_builtin(__builtin_amdgcn_exp2f)
  return __builtin_amdgcn_exp2f(x);
#else
  return exp2f(x);
#endif
}

__device__ __forceinline__ unsigned cvtpk(float lo, float hi) {
  unsigned r;
  asm volatile("v_cvt_pk_bf16_f32 %0, %1, %2" : "=v"(r) : "v"(lo), "v"(hi));
  return r;
}

// a' = {a.lo32, b.lo32}, b' = {a.hi32, b.hi32}
__device__ __forceinline__ void lane_swap32(unsigned &a, unsigned &b) {
#if __has_builtin(__builtin_amdgcn_permlane32_swap)
  auto r = __builtin_amdgcn_permlane32_swap(a, b, false, false);
  a = r[0]; b = r[1];
#else
  const bool hi = (threadIdx.x & 32) != 0;
  unsigned sa = (unsigned)__shfl_xor((int)a, 32, 64);
  unsigned sb = (unsigned)__shfl_xor((int)b, 32, 64);
  unsigned na = hi ? sb : a;
  unsigned nb = hi ? b : sa;
  a = na; b = nb;
#endif
}

// a' = {a.g0, b.g0, a.g2, b.g2}, b' = {a.g1, b.g1, a.g3, b.g3} (16-lane groups)
__device__ __forceinline__ void lane_swap16(unsigned &a, unsigned &b) {
#if __has_builtin(__builtin_amdgcn_permlane16_swap)
  auto r = __builtin_amdgcn_permlane16_swap(a, b, false, false);
  a = r[0]; b = r[1];
#else
  const bool odd = (threadIdx.x & 16) != 0;
  unsigned sa = (unsigned)__shfl_xor((int)a, 16, 64);
  unsigned sb = (unsigned)__shfl_xor((int)b, 16, 64);
  unsigned na = odd ? sb : a;
  unsigned nb = odd ? b : sa;
  a = na; b = nb;
#endif
}

__device__ __forceinline__ void gload_lds16(const void* g, void* l) {
  __builtin_amdgcn_global_load_lds((const __attribute__((address_space(1))) void*)g,
                                   (__attribute__((address_space(3))) void*)l,
                                   16, 0, 0);
}

// ---------------- fp32 -> bf16 convert ----------------
__global__ __launch_bounds__(256) void k_cvt(const float* __restrict__ src,
                                             unsigned short* __restrict__ dst, int n4) {
  int i = blockIdx.x * 256 + threadIdx.x;
  if (i >= n4) return;
  const float4 v = ((const float4*)src)[i];
  ushort4 o;
  o.x = f2bf(v.x); o.y = f2bf(v.y); o.z = f2bf(v.z); o.w = f2bf(v.w);
  ((ushort4*)dst)[i] = o;
}

// ---------------- GEMM1: X[8192][1024] x W1t[3072][1024] -> scatter Q/K/V ----------------
__global__ __launch_bounds__(256, 2) void k_gemm_qkv(
    const unsigned short* __restrict__ A,
    const unsigned short* __restrict__ Bt,
    unsigned short* __restrict__ Qb,        // [64][2048][64]
    unsigned short* __restrict__ Kb,        // [64][2048][64]
    unsigned short* __restrict__ Vb) {      // [64][2048][64]
  constexpr int K = 1024;
  __shared__ __align__(16) unsigned short As[128 * 32];
  __shared__ __align__(16) unsigned short Bs[128 * 32];
  const int tid = threadIdx.x;
  const int l = tid & 63, w = tid >> 6;
  const int lr = l & 15, lg = l >> 4;
  const int bm = blockIdx.x, bn = blockIdx.y;
  const int wr = (w >> 1) * 64, wc = (w & 1) * 64;

  f32x4 acc[4][4] = {};

  const int o0 = tid * 16, o1 = tid * 16 + 4096;
  const int r0 = o0 >> 6, c0 = o0 & 63;
  const int r1 = o1 >> 6, c1 = o1 & 63;
  const char* gA0 = (const char*)A + (size_t)(bm * 128 + r0) * (K * 2) + c0;
  const char* gA1 = (const char*)A + (size_t)(bm * 128 + r1) * (K * 2) + c1;
  const char* gB0 = (const char*)Bt + (size_t)(bn * 128 + r0) * (K * 2) + c0;
  const char* gB1 = (const char*)Bt + (size_t)(bn * 128 + r1) * (K * 2) + c1;
  char* lA0 = (char*)As + o0;
  char* lA1 = (char*)As + o1;
  char* lB0 = (char*)Bs + o0;
  char* lB1 = (char*)Bs + o1;

  for (int kt = 0; kt < K / 32; ++kt) {
    const int kb = kt * 64;
    gload_lds16(gA0 + kb, lA0);
    gload_lds16(gA1 + kb, lA1);
    gload_lds16(gB0 + kb, lB0);
    gload_lds16(gB1 + kb, lB1);
    __syncthreads();
    bf16x8 af[4], bfr[4];
#pragma unroll
    for (int mf = 0; mf < 4; ++mf)
      af[mf] = *(const bf16x8*)&As[(wr + mf * 16 + lr) * 32 + lg * 8];
#pragma unroll
    for (int nf = 0; nf < 4; ++nf)
      bfr[nf] = *(const bf16x8*)&Bs[(wc + nf * 16 + lr) * 32 + lg * 8];
#pragma unroll
    for (int mf = 0; mf < 4; ++mf)
#pragma unroll
      for (int nf = 0; nf < 4; ++nf)
        acc[mf][nf] = MFMA16(af[mf], bfr[nf], acc[mf][nf]);
    __syncthreads();
  }

  // D layout: col = lane&15, row = (lane>>4)*4 + i. Coalesced [n][t][d] for Q,K,V.
#pragma unroll
  for (int nf = 0; nf < 4; ++nf) {
    const int f = bn * 128 + wc + nf * 16 + lr;
    const int hq = f / 192;
    const int s3 = (f >> 6) % 3;
    const int d = f & 63;
    unsigned short* dst = (s3 == 0) ? Qb : (s3 == 1) ? Kb : Vb;
    // fold SCALE*log2(e) into Q so softmax is a bare exp2
    const float qscale = (s3 == 0) ? 0.18033688011112042f : 1.0f;
#pragma unroll
    for (int mf = 0; mf < 4; ++mf) {
#pragma unroll
      for (int i = 0; i < 4; ++i) {
        const int r = bm * 128 + wr + mf * 16 + lg * 4 + i;
        const int t = r >> 2, bb2 = r & 3;
        const int nIdx = bb2 * 16 + hq;
        dst[((size_t)nIdx * 2048 + t) * 64 + d] = f2bf(acc[mf][nf][i] * qscale);
      }
    }
  }
}

// ---------------- V transpose: [n][t][d] -> [n][d][t] ----------------
__global__ __launch_bounds__(256) void k_vtrans(const unsigned short* __restrict__ V,
                                                unsigned short* __restrict__ VT) {
  __shared__ unsigned short tile[64][66];
  const int tid = threadIdx.x;
  const int n = blockIdx.y, t0 = blockIdx.x * 64;
  const int r = tid >> 2, c0 = (tid & 3) * 16;
  const unsigned short* src = V + ((size_t)(n * 2048 + t0 + r) * 64 + c0);
  bf16x8 a = *(const bf16x8*)src;
  bf16x8 b = *(const bf16x8*)(src + 8);
#pragma unroll
  for (int j = 0; j < 8; ++j) tile[r][c0 + j] = (unsigned short)a[j];
#pragma unroll
  for (int j = 0; j < 8; ++j) tile[r][c0 + 8 + j] = (unsigned short)b[j];
  __syncthreads();
  const int d = tid >> 2, u0 = (tid & 3) * 16;
  bf16x8 oA, oB;
#pragma unroll
  for (int j = 0; j < 8; ++j) oA[j] = (short)tile[u0 + j][d];
#pragma unroll
  for (int j = 0; j < 8; ++j) oB[j] = (short)tile[u0 + 8 + j][d];
  unsigned short* dst = VT + ((size_t)(n * 64 + d) * 2048 + t0 + u0);
  *(bf16x8*)dst = oA;
  *(bf16x8*)(dst + 8) = oB;
}

// ---------------- flash attention: q=128/block, 4 blocks/CU, 2-phase pipelined ----------------
__global__ __launch_bounds__(256, 4) void k_attn(
    const unsigned short* __restrict__ Qb, const unsigned short* __restrict__ Kb,
    const unsigned short* __restrict__ VTb, unsigned short* __restrict__ Cx) {
  __shared__ __align__(16) unsigned short Ks[2][64 * 64];  // [s][d], xor-swizzled
  __shared__ __align__(16) unsigned short Vt[2][64 * 64];  // [d][s], xor-swizzled

  const int tid = threadIdx.x;
  const int l = tid & 63, w = tid >> 6;
  const int lq = l & 15, lg = l >> 4;
  const int n = blockIdx.x, qt = blockIdx.y;   // x = head -> same-head blocks on one XCD

  const unsigned short* Qh = Qb + (size_t)n * (2048 * 64);
  const unsigned short* Kh = Kb + (size_t)n * (2048 * 64);
  const unsigned short* Vh = VTb + (size_t)n * (64 * 2048);

  // Q fragments (B-operand of swapped QK^T): q = qt*128 + w*32 + qf*16 + lq
  bf16x8 aq[2][2];
#pragma unroll
  for (int qf = 0; qf < 2; ++qf)
#pragma unroll
    for (int kd = 0; kd < 2; ++kd)
      aq[qf][kd] = *(const bf16x8*)&Qh[(size_t)(qt * 128 + w * 32 + qf * 16 + lq) * 64 +
                                       kd * 32 + lg * 8];

  f32x4 o[4][2] = {};       // O^T acc: [df][qf]; lane: q = lq, d = df*16 + lg*4 + i
  float lsum[2] = {0.f, 0.f};

  char* Ksl = (char*)&Ks[0][0];
  char* Vtl = (char*)&Vt[0][0];

  auto STAGE = [&](int buf, int st) {
    const int s0 = st * 64;
#pragma unroll
    for (int it = 0; it < 2; ++it) {
      const int off = (it * 256 + tid) * 16;
      const int row = off >> 7;
      const int colb = (off & 127) ^ ((row & 7) << 4);
      gload_lds16((const char*)Kh + ((size_t)(s0 + row) << 7) + colb, Ksl + buf * 8192 + off);
      gload_lds16((const char*)Vh + ((size_t)row << 12) + (s0 << 1) + colb, Vtl + buf * 8192 + off);
    }
  };

  STAGE(0, 0);
  asm volatile("s_waitcnt vmcnt(0)" ::: "memory");
  __builtin_amdgcn_s_barrier();

#pragma unroll 2
  for (int st = 0; st < 32; ++st) {
    const int cur = st & 1;
    if (st + 1 < 32) STAGE(cur ^ 1, st + 1);   // prefetch next tile (in flight during compute)

    const char* Kc = Ksl + cur * 8192;
    const char* Vc = Vtl + cur * 8192;

    __builtin_amdgcn_s_setprio(1);
#pragma unroll
    for (int kb = 0; kb < 2; ++kb) {
      // K fragments for s-block [kb*32, kb*32+32): rows (2kb+sfl)*16 + lq
      bf16x8 kf[2][2];
#pragma unroll
      for (int sfl = 0; sfl < 2; ++sfl) {
        const int rowk = (2 * kb + sfl) * 16 + lq;
        const int sw = (rowk & 7) << 4;
        kf[sfl][0] = *(const bf16x8*)(Kc + ((rowk * 128 + lg * 16) ^ sw));
        kf[sfl][1] = *(const bf16x8*)(Kc + ((rowk * 128 + 64 + lg * 16) ^ sw));
      }

      // QK^T + softmax + in-register P->B-frag exchange, per qf
      bf16x8 pq[2];
#pragma unroll
      for (int qf = 0; qf < 2; ++qf) {
        f32x4 s0 = {0.f, 0.f, 0.f, 0.f};
        f32x4 s1 = {0.f, 0.f, 0.f, 0.f};
        s0 = MFMA16(kf[0][0], aq[qf][0], s0);
        s0 = MFMA16(kf[0][1], aq[qf][1], s0);
        s1 = MFMA16(kf[1][0], aq[qf][0], s1);
        s1 = MFMA16(kf[1][1], aq[qf][1], s1);
        float accs = 0.f;
#pragma unroll
        for (int i = 0; i < 4; ++i) {
          s0[i] = fast_exp2(s0[i]);
          s1[i] = fast_exp2(s1[i]);
          accs += s0[i] + s1[i];
        }
        lsum[qf] += accs;
        unsigned w0 = cvtpk(s0[0], s0[1]);
        unsigned w1 = cvtpk(s0[2], s0[3]);
        unsigned w2 = cvtpk(s1[0], s1[1]);
        unsigned w3 = cvtpk(s1[2], s1[3]);
        lane_swap32(w0, w2);
        lane_swap32(w1, w3);
        lane_swap16(w0, w2);
        lane_swap16(w1, w3);
        u32x4 t4 = {w0, w1, w2, w3};
        pq[qf] = __builtin_bit_cast(bf16x8, t4);
      }

      // PV for this s-block: O^T += V^T(:, kb) . P^T
#pragma unroll
      for (int df = 0; df < 4; ++df) {
        const int rowd = df * 16 + lq;
        const int sw = (rowd & 7) << 4;
        bf16x8 vf = *(const bf16x8*)(Vc + ((rowd * 128 + kb * 64 + lg * 16) ^ sw));
#pragma unroll
        for (int qf = 0; qf < 2; ++qf)
          o[df][qf] = MFMA16(vf, pq[qf], o[df][qf]);
      }
    }
    __builtin_amdgcn_s_setprio(0);

    asm volatile("s_waitcnt vmcnt(0)" ::: "memory");
    __builtin_amdgcn_s_barrier();
  }

  // epilogue: reduce lsum over lane-groups, normalize, store
  const int bb = n >> 4, h = n & 15;
#pragma unroll
  for (int qf = 0; qf < 2; ++qf) {
    float li = lsum[qf];
    li += __shfl_xor(li, 16, 64);
    li += __shfl_xor(li, 32, 64);
    const float inv = 1.0f / li;
    const int q = qt * 128 + w * 32 + qf * 16 + lq;
#pragma unroll
    for (int df = 0; df < 4; ++df) {
      ushort4 pk;
      pk.x = f2bf(o[df][qf][0] * inv);
      pk.y = f2bf(o[df][qf][1] * inv);
      pk.z = f2bf(o[df][qf][2] * inv);
      pk.w = f2bf(o[df][qf][3] * inv);
      *(ushort4*)&Cx[(size_t)(q * 4 + bb) * 1024 + h * 64 + df * 16 + lg * 4] = pk;
    }
  }
}

// ---------------- GEMM4: ctx[8192][1024] x Wot[1024][1024] -> out fp32 ----------------
__global__ __launch_bounds__(256, 2) void k_gemm_out(
    const unsigned short* __restrict__ A,
    const unsigned short* __restrict__ Bt,
    float* __restrict__ C) {
  constexpr int K = 1024;
  __shared__ __align__(16) unsigned short As[128 * 32];
  __shared__ __align__(16) unsigned short Bs[128 * 32];
  const int tid = threadIdx.x;
  const int l = tid & 63, w = tid >> 6;
  const int lr = l & 15, lg = l >> 4;
  const int bm = blockIdx.x, bn = blockIdx.y;
  const int wr = (w >> 1) * 64, wc = (w & 1) * 64;

  f32x4 acc[4][4] = {};

  const int o0 = tid * 16, o1 = tid * 16 + 4096;
  const int r0 = o0 >> 6, c0 = o0 & 63;
  const int r1 = o1 >> 6, c1 = o1 & 63;
  const char* gA0 = (const char*)A + (size_t)(bm * 128 + r0) * (K * 2) + c0;
  const char* gA1 = (const char*)A + (size_t)(bm * 128 + r1) * (K * 2) + c1;
  const char* gB0 = (const char*)Bt + (size_t)(bn * 128 + r0) * (K * 2) + c0;
  const char* gB1 = (const char*)Bt + (size_t)(bn * 128 + r1) * (K * 2) + c1;
  char* lA0 = (char*)As + o0;
  char* lA1 = (char*)As + o1;
  char* lB0 = (char*)Bs + o0;
  char* lB1 = (char*)Bs + o1;

  for (int kt = 0; kt < K / 32; ++kt) {
    const int kb = kt * 64;
    gload_lds16(gA0 + kb, lA0);
    gload_lds16(gA1 + kb, lA1);
    gload_lds16(gB0 + kb, lB0);
    gload_lds16(gB1 + kb, lB1);
    __syncthreads();
    bf16x8 af[4], bfr[4];
#pragma unroll
    for (int mf = 0; mf < 4; ++mf)
      af[mf] = *(const bf16x8*)&As[(wr + mf * 16 + lr) * 32 + lg * 8];
#pragma unroll
    for (int nf = 0; nf < 4; ++nf)
      bfr[nf] = *(const bf16x8*)&Bs[(wc + nf * 16 + lr) * 32 + lg * 8];
#pragma unroll
    for (int mf = 0; mf < 4; ++mf)
#pragma unroll
      for (int nf = 0; nf < 4; ++nf)
        acc[mf][nf] = MFMA16(af[mf], bfr[nf], acc[mf][nf]);
    __syncthreads();
  }

#pragma unroll
  for (int mf = 0; mf < 4; ++mf)
#pragma unroll
    for (int i = 0; i < 4; ++i) {
      const int r = bm * 128 + wr + mf * 16 + lg * 4 + i;
#pragma unroll
      for (int nf = 0; nf < 4; ++nf)
        C[(size_t)r * 1024 + bn * 128 + wc + nf * 16 + lr] = acc[mf][nf][i];
    }
}

// ---------------- host launch ----------------
extern "C" void kernel_launch(void* const* d_in, const int* in_sizes, int n_in,
                              void* d_out, int out_size, void* d_ws, size_t ws_size,
                              hipStream_t stream) {
  const float* X = (const float*)d_in[0];    // (2048,4,1024)
  const float* W1 = (const float*)d_in[1];   // (3072,1024)
  const float* Wo = (const float*)d_in[2];   // (1024,1024)
  float* out = (float*)d_out;                // (2048,4,1024) fp32

  char* ws = (char*)d_ws;
  unsigned short* Xb  = (unsigned short*)(ws);              // 16 MB
  unsigned short* W1b = (unsigned short*)(ws + 16777216);   //  6 MB
  unsigned short* Wob = (unsigned short*)(ws + 23068672);   //  2 MB
  unsigned short* Qb  = (unsigned short*)(ws + 25165824);   // 16 MB
  unsigned short* Kb  = (unsigned short*)(ws + 41943040);   // 16 MB
  unsigned short* VTb = (unsigned short*)(ws + 58720256);   // 16 MB
  // Vb aliases the Cx slot: Vb is dead after k_vtrans, Cx written only by k_attn (later).
  unsigned short* Vb  = (unsigned short*)(ws + 75497472);   // 16 MB
  unsigned short* Cx  = (unsigned short*)(ws + 75497472);   // same 16 MB

  k_cvt<<<8192, 256, 0, stream>>>(X, Xb, 2097152);
  k_cvt<<<3072, 256, 0, stream>>>(W1, W1b, 786432);
  k_cvt<<<1024, 256, 0, stream>>>(Wo, Wob, 262144);
  k_gemm_qkv<<<dim3(64, 24), 256, 0, stream>>>(Xb, W1b, Qb, Kb, Vb);
  k_vtrans<<<dim3(32, 64), 256, 0, stream>>>(Vb, VTb);
  k_attn<<<dim3(64, 16), 256, 0, stream>>>(Qb, Kb, VTb, Cx);
  k_gemm_out<<<dim3(64, 8), 256, 0, stream>>>(Cx, Wob, out);
}

// Round 10
// 199.884 us; speedup vs baseline: 1.1105x; 1.0401x over previous
//
#include <hip/hip_runtime.h>
#include <stdint.h>
#include <stddef.h>

// T=2048, B=4, E=1024, H=16, HD=64, N-heads = B*H = 64.
// qkv reshape: f in [0,3072) -> head hq = f/192, s3 = (f/64)%3, d = f%64, n = b*16+hq.
// Layouts: Qb,Kb,Vb = [n][t][d] bf16 ; VTb = [n][d][t] bf16 (separate transpose kernel).

typedef __attribute__((ext_vector_type(8))) short bf16x8;
typedef __attribute__((ext_vector_type(4))) float f32x4;
typedef __attribute__((ext_vector_type(4))) unsigned int u32x4;

#define MFMA16(a, b, c) __builtin_amdgcn_mfma_f32_16x16x32_bf16((a), (b), (c), 0, 0, 0)

__device__ __forceinline__ unsigned short f2bf(float f) {
  unsigned u = __builtin_bit_cast(unsigned, f);
  u += 0x7fffu + ((u >> 16) & 1u);   // RNE
  return (unsigned short)(u >> 16);
}

__device__ __forceinline__ float fast_exp2(float x) {
#if __has_builtin(__builtin_amdgcn_exp2f)
  return __builtin_amdgcn_exp2f(x);
#else
  return exp2f(x);
#endif
}

__device__ __forceinline__ unsigned cvtpk(float lo, float hi) {
  unsigned r;
  asm volatile("v_cvt_pk_bf16_f32 %0, %1, %2" : "=v"(r) : "v"(lo), "v"(hi));
  return r;
}

// a' = {a.lo32, b.lo32}, b' = {a.hi32, b.hi32}
__device__ __forceinline__ void lane_swap32(unsigned &a, unsigned &b) {
#if __has_builtin(__builtin_amdgcn_permlane32_swap)
  auto r = __builtin_amdgcn_permlane32_swap(a, b, false, false);
  a = r[0]; b = r[1];
#else
  const bool hi = (threadIdx.x & 32) != 0;
  unsigned sa = (unsigned)__shfl_xor((int)a, 32, 64);
  unsigned sb = (unsigned)__shfl_xor((int)b, 32, 64);
  unsigned na = hi ? sb : a;
  unsigned nb = hi ? b : sa;
  a = na; b = nb;
#endif
}

// a' = {a.g0, b.g0, a.g2, b.g2}, b' = {a.g1, b.g1, a.g3, b.g3} (16-lane groups)
__device__ __forceinline__ void lane_swap16(unsigned &a, unsigned &b) {
#if __has_builtin(__builtin_amdgcn_permlane16_swap)
  auto r = __builtin_amdgcn_permlane16_swap(a, b, false, false);
  a = r[0]; b = r[1];
#else
  const bool odd = (threadIdx.x & 16) != 0;
  unsigned sa = (unsigned)__shfl_xor((int)a, 16, 64);
  unsigned sb = (unsigned)__shfl_xor((int)b, 16, 64);
  unsigned na = odd ? sb : a;
  unsigned nb = odd ? b : sa;
  a = na; b = nb;
#endif
}

__device__ __forceinline__ void gload_lds16(const void* g, void* l) {
  __builtin_amdgcn_global_load_lds((const __attribute__((address_space(1))) void*)g,
                                   (__attribute__((address_space(3))) void*)l,
                                   16, 0, 0);
}

__device__ __forceinline__ void cfence() { asm volatile("" ::: "memory"); }

// ---------------- fp32 -> bf16 convert ----------------
__global__ __launch_bounds__(256) void k_cvt(const float* __restrict__ src,
                                             unsigned short* __restrict__ dst, int n4) {
  int i = blockIdx.x * 256 + threadIdx.x;
  if (i >= n4) return;
  const float4 v = ((const float4*)src)[i];
  ushort4 o;
  o.x = f2bf(v.x); o.y = f2bf(v.y); o.z = f2bf(v.z); o.w = f2bf(v.w);
  ((ushort4*)dst)[i] = o;
}

// ---------------- GEMM1: 256x256 tile, 8 waves, 4-phase counted-vmcnt schedule ----------------
// Sync discipline: stage-issue ... vmcnt(N) -> barrier -> ds_read  (wait BEFORE the barrier,
// so after the barrier ALL waves' loads for the consumed unit are complete).
__global__ __launch_bounds__(512, 2) void k_gemm_qkv(
    const unsigned short* __restrict__ A,
    const unsigned short* __restrict__ Bt,
    unsigned short* __restrict__ Qb,        // [64][2048][64]
    unsigned short* __restrict__ Kb,        // [64][2048][64]
    unsigned short* __restrict__ Vb) {      // [64][2048][64]
  // LDS: [2 dbuf][2 k-units][256 rows][32 k] bf16 per operand = 64KB each, 128KB total.
  // Swizzle: byte col ^= ((row>>1)&3)<<4.
  __shared__ __align__(16) unsigned short As[2][2][256 * 32];
  __shared__ __align__(16) unsigned short Bs[2][2][256 * 32];

  const int tid = threadIdx.x;            // 0..511
  const int l = tid & 63;
  const int wid = tid >> 6;               // 0..7
  const int lr = l & 15, lg = l >> 4;
  const int wr = wid >> 2, wc = wid & 3;  // 2M x 4N wave grid
  const int bm = blockIdx.x, bn = blockIdx.y;

  f32x4 acc[8][4] = {};                   // per-wave 128x64 output

  const int colF = (lg * 16) ^ (((lr >> 1) & 3) << 4);

  // stage one 16KB unit (256 rows x 64B), 2 gload_lds per thread, pre-swizzled source
  auto STAGE = [&](unsigned short* lds_unit, const unsigned short* gbase, int grow0,
                   int kt2, int uk) {
#pragma unroll
    for (int i = 0; i < 2; ++i) {
      const int idx = i * 512 + tid;           // 0..1023
      const int row = idx >> 2;                // 0..255
      const int colb = (idx & 3) * 16;         // 0,16,32,48
      const int sw = ((row >> 1) & 3) << 4;
      gload_lds16((const char*)gbase + (size_t)(grow0 + row) * 2048 + kt2 * 128 +
                      uk * 64 + (colb ^ sw),
                  (char*)lds_unit + idx * 16);
    }
  };

  auto LDA4 = [&](int buf, int uk, int mhalf, bf16x8* d) {
#pragma unroll
    for (int mf = 0; mf < 4; ++mf) {
      const int row = wr * 128 + (mhalf * 4 + mf) * 16 + lr;
      d[mf] = *(const bf16x8*)((const char*)&As[buf][uk][0] + row * 64 + colF);
    }
  };
  auto LDB4 = [&](int buf, int uk, bf16x8* d) {
#pragma unroll
    for (int nf = 0; nf < 4; ++nf) {
      const int row = wc * 64 + nf * 16 + lr;
      d[nf] = *(const bf16x8*)((const char*)&Bs[buf][uk][0] + row * 64 + colF);
    }
  };

  // prologue: stage all 4 units of step 0 into buf 0 (issue order = wait order),
  // then wait for u0 (oldest 4 loads) and BARRIER so all waves' u0 is complete.
  STAGE(&As[0][0][0], A, bm * 256, 0, 0);
  STAGE(&Bs[0][0][0], Bt, bn * 256, 0, 0);
  STAGE(&As[0][1][0], A, bm * 256, 0, 1);
  STAGE(&Bs[0][1][0], Bt, bn * 256, 0, 1);
  asm volatile("s_waitcnt vmcnt(4)" ::: "memory");
  __builtin_amdgcn_s_barrier();
  cfence();

#pragma unroll 2
  for (int kt = 0; kt < 16; ++kt) {
    const int buf = kt & 1, nbuf = buf ^ 1;
    const int ktn = (kt + 1 < 16) ? kt + 1 : 15;   // tail: dummy re-stage keeps vmcnt uniform

    // ---- phase 0: k-unit 0, M-half 0 (u0 complete: prev ph3's vmcnt+barrier) ----
    bf16x8 a0[4], b0[4];
    LDA4(buf, 0, 0, a0);
    LDB4(buf, 0, b0);
    STAGE(&As[nbuf][0][0], A, bm * 256, ktn, 0);
    __builtin_amdgcn_s_setprio(1);
#pragma unroll
    for (int mf = 0; mf < 4; ++mf)
#pragma unroll
      for (int nf = 0; nf < 4; ++nf)
        acc[mf][nf] = MFMA16(a0[mf], b0[nf], acc[mf][nf]);
    __builtin_amdgcn_s_setprio(0);
    cfence();
    __builtin_amdgcn_s_barrier();
    cfence();

    // ---- phase 1: k-unit 0, M-half 1 (reuse b0) ----
    bf16x8 a1[4];
    LDA4(buf, 0, 1, a1);
    STAGE(&Bs[nbuf][0][0], Bt, bn * 256, ktn, 0);
    __builtin_amdgcn_s_setprio(1);
#pragma unroll
    for (int mf = 0; mf < 4; ++mf)
#pragma unroll
      for (int nf = 0; nf < 4; ++nf)
        acc[4 + mf][nf] = MFMA16(a1[mf], b0[nf], acc[4 + mf][nf]);
    __builtin_amdgcn_s_setprio(0);
    // drain u1 of current step (oldest 4 of the 8 outstanding), THEN barrier
    asm volatile("s_waitcnt vmcnt(4)" ::: "memory");
    __builtin_amdgcn_s_barrier();
    cfence();

    // ---- phase 2: k-unit 1, M-half 0 (u1 complete for ALL waves) ----
    bf16x8 a2[4], b1[4];
    LDA4(buf, 1, 0, a2);
    LDB4(buf, 1, b1);
    STAGE(&As[nbuf][1][0], A, bm * 256, ktn, 1);
    __builtin_amdgcn_s_setprio(1);
#pragma unroll
    for (int mf = 0; mf < 4; ++mf)
#pragma unroll
      for (int nf = 0; nf < 4; ++nf)
        acc[mf][nf] = MFMA16(a2[mf], b1[nf], acc[mf][nf]);
    __builtin_amdgcn_s_setprio(0);
    cfence();
    __builtin_amdgcn_s_barrier();
    cfence();

    // ---- phase 3: k-unit 1, M-half 1 (reuse b1) ----
    bf16x8 a3[4];
    LDA4(buf, 1, 1, a3);
    STAGE(&Bs[nbuf][1][0], Bt, bn * 256, ktn, 1);
    __builtin_amdgcn_s_setprio(1);
#pragma unroll
    for (int mf = 0; mf < 4; ++mf)
#pragma unroll
      for (int nf = 0; nf < 4; ++nf)
        acc[4 + mf][nf] = MFMA16(a3[mf], b1[nf], acc[4 + mf][nf]);
    __builtin_amdgcn_s_setprio(0);
    // drain u0 of NEXT step, THEN barrier -> next ph0's reads are safe for all waves
    asm volatile("s_waitcnt vmcnt(4)" ::: "memory");
    __builtin_amdgcn_s_barrier();
    cfence();
  }

  // Epilogue: D layout col = lane&15, row = (lane>>4)*4 + i. Scatter to Q/K/V.
#pragma unroll
  for (int nf = 0; nf < 4; ++nf) {
    const int f = bn * 256 + wc * 64 + nf * 16 + lr;
    const int hq = f / 192;
    const int s3 = (f >> 6) % 3;
    const int d = f & 63;
    unsigned short* dst = (s3 == 0) ? Qb : (s3 == 1) ? Kb : Vb;
    // fold SCALE*log2(e) into Q so softmax is a bare exp2
    const float qscale = (s3 == 0) ? 0.18033688011112042f : 1.0f;
#pragma unroll
    for (int mq = 0; mq < 8; ++mq) {
#pragma unroll
      for (int i = 0; i < 4; ++i) {
        const int r = bm * 256 + wr * 128 + mq * 16 + lg * 4 + i;
        const int t = r >> 2, bb2 = r & 3;
        const int nIdx = bb2 * 16 + hq;
        dst[((size_t)nIdx * 2048 + t) * 64 + d] = f2bf(acc[mq][nf][i] * qscale);
      }
    }
  }
}

// ---------------- V transpose: [n][t][d] -> [n][d][t] ----------------
__global__ __launch_bounds__(256) void k_vtrans(const unsigned short* __restrict__ V,
                                                unsigned short* __restrict__ VT) {
  __shared__ unsigned short tile[64][66];
  const int tid = threadIdx.x;
  const int n = blockIdx.y, t0 = blockIdx.x * 64;
  const int r = tid >> 2, c0 = (tid & 3) * 16;
  const unsigned short* src = V + ((size_t)(n * 2048 + t0 + r) * 64 + c0);
  bf16x8 a = *(const bf16x8*)src;
  bf16x8 b = *(const bf16x8*)(src + 8);
#pragma unroll
  for (int j = 0; j < 8; ++j) tile[r][c0 + j] = (unsigned short)a[j];
#pragma unroll
  for (int j = 0; j < 8; ++j) tile[r][c0 + 8 + j] = (unsigned short)b[j];
  __syncthreads();
  const int d = tid >> 2, u0 = (tid & 3) * 16;
  bf16x8 oA, oB;
#pragma unroll
  for (int j = 0; j < 8; ++j) oA[j] = (short)tile[u0 + j][d];
#pragma unroll
  for (int j = 0; j < 8; ++j) oB[j] = (short)tile[u0 + 8 + j][d];
  unsigned short* dst = VT + ((size_t)(n * 64 + d) * 2048 + t0 + u0);
  *(bf16x8*)dst = oA;
  *(bf16x8*)(dst + 8) = oB;
}

// ---------------- flash attention: q=256/block, 2-phase pipelined (R5 verified) ----------------
__global__ __launch_bounds__(256, 2) void k_attn(
    const unsigned short* __restrict__ Qb, const unsigned short* __restrict__ Kb,
    const unsigned short* __restrict__ VTb, unsigned short* __restrict__ Cx) {
  __shared__ __align__(16) unsigned short Ks[2][64 * 64];  // [s][d], xor-swizzled
  __shared__ __align__(16) unsigned short Vt[2][64 * 64];  // [d][s], xor-swizzled

  const int tid = threadIdx.x;
  const int l = tid & 63, w = tid >> 6;
  const int lq = l & 15, lg = l >> 4;
  const int n = blockIdx.x, qt = blockIdx.y;   // x = head -> same-head blocks on one XCD

  const unsigned short* Qh = Qb + (size_t)n * (2048 * 64);
  const unsigned short* Kh = Kb + (size_t)n * (2048 * 64);
  const unsigned short* Vh = VTb + (size_t)n * (64 * 2048);

  // Q fragments (B-operand of swapped QK^T): q = qt*256 + w*64 + qf*16 + lq
  bf16x8 aq[4][2];
#pragma unroll
  for (int qf = 0; qf < 4; ++qf)
#pragma unroll
    for (int kd = 0; kd < 2; ++kd)
      aq[qf][kd] = *(const bf16x8*)&Qh[(size_t)(qt * 256 + w * 64 + qf * 16 + lq) * 64 +
                                       kd * 32 + lg * 8];

  f32x4 o[4][4] = {};       // O^T acc: [df][qf]; lane: q = lq, d = df*16 + lg*4 + i
  float lsum[4] = {0.f, 0.f, 0.f, 0.f};

  char* Ksl = (char*)&Ks[0][0];
  char* Vtl = (char*)&Vt[0][0];

  auto STAGE = [&](int buf, int st) {
    const int s0 = st * 64;
#pragma unroll
    for (int it = 0; it < 2; ++it) {
      const int off = (it * 256 + tid) * 16;
      const int row = off >> 7;
      const int colb = (off & 127) ^ ((row & 7) << 4);
      gload_lds16((const char*)Kh + ((size_t)(s0 + row) << 7) + colb, Ksl + buf * 8192 + off);
      gload_lds16((const char*)Vh + ((size_t)row << 12) + (s0 << 1) + colb, Vtl + buf * 8192 + off);
    }
  };

  STAGE(0, 0);
  asm volatile("s_waitcnt vmcnt(0)" ::: "memory");
  __builtin_amdgcn_s_barrier();

#pragma unroll 2
  for (int st = 0; st < 32; ++st) {
    const int cur = st & 1;
    if (st + 1 < 32) STAGE(cur ^ 1, st + 1);   // prefetch next tile

    const char* Kc = Ksl + cur * 8192;
    const char* Vc = Vtl + cur * 8192;

    __builtin_amdgcn_s_setprio(1);
#pragma unroll
    for (int kb = 0; kb < 2; ++kb) {
      // K fragments for s-block [kb*32, kb*32+32): rows (2kb+sfl)*16 + lq
      bf16x8 kf[2][2];
#pragma unroll
      for (int sfl = 0; sfl < 2; ++sfl) {
        const int rowk = (2 * kb + sfl) * 16 + lq;
        const int sw = (rowk & 7) << 4;
        kf[sfl][0] = *(const bf16x8*)(Kc + ((rowk * 128 + lg * 16) ^ sw));
        kf[sfl][1] = *(const bf16x8*)(Kc + ((rowk * 128 + 64 + lg * 16) ^ sw));
      }

      // QK^T + softmax + in-register P->B-frag exchange, per qf
      bf16x8 pq[4];
#pragma unroll
      for (int qf = 0; qf < 4; ++qf) {
        f32x4 s0 = {0.f, 0.f, 0.f, 0.f};
        f32x4 s1 = {0.f, 0.f, 0.f, 0.f};
        s0 = MFMA16(kf[0][0], aq[qf][0], s0);
        s0 = MFMA16(kf[0][1], aq[qf][1], s0);
        s1 = MFMA16(kf[1][0], aq[qf][0], s1);
        s1 = MFMA16(kf[1][1], aq[qf][1], s1);
        float accs = 0.f;
#pragma unroll
        for (int i = 0; i < 4; ++i) {
          s0[i] = fast_exp2(s0[i]);
          s1[i] = fast_exp2(s1[i]);
          accs += s0[i] + s1[i];
        }
        lsum[qf] += accs;
        unsigned w0 = cvtpk(s0[0], s0[1]);
        unsigned w1 = cvtpk(s0[2], s0[3]);
        unsigned w2 = cvtpk(s1[0], s1[1]);
        unsigned w3 = cvtpk(s1[2], s1[3]);
        lane_swap32(w0, w2);
        lane_swap32(w1, w3);
        lane_swap16(w0, w2);
        lane_swap16(w1, w3);
        u32x4 t4 = {w0, w1, w2, w3};
        pq[qf] = __builtin_bit_cast(bf16x8, t4);
      }

      // PV for this s-block: O^T += V^T(:, kb) . P^T
#pragma unroll
      for (int df = 0; df < 4; ++df) {
        const int rowd = df * 16 + lq;
        const int sw = (rowd & 7) << 4;
        bf16x8 vf = *(const bf16x8*)(Vc + ((rowd * 128 + kb * 64 + lg * 16) ^ sw));
#pragma unroll
        for (int qf = 0; qf < 4; ++qf)
          o[df][qf] = MFMA16(vf, pq[qf], o[df][qf]);
      }
    }
    __builtin_amdgcn_s_setprio(0);

    asm volatile("s_waitcnt vmcnt(0)" ::: "memory");
    __builtin_amdgcn_s_barrier();
  }

  // epilogue: reduce lsum over lane-groups, normalize, store
  const int bb = n >> 4, h = n & 15;
#pragma unroll
  for (int qf = 0; qf < 4; ++qf) {
    float li = lsum[qf];
    li += __shfl_xor(li, 16, 64);
    li += __shfl_xor(li, 32, 64);
    const float inv = 1.0f / li;
    const int q = qt * 256 + w * 64 + qf * 16 + lq;
#pragma unroll
    for (int df = 0; df < 4; ++df) {
      ushort4 pk;
      pk.x = f2bf(o[df][qf][0] * inv);
      pk.y = f2bf(o[df][qf][1] * inv);
      pk.z = f2bf(o[df][qf][2] * inv);
      pk.w = f2bf(o[df][qf][3] * inv);
      *(ushort4*)&Cx[(size_t)(q * 4 + bb) * 1024 + h * 64 + df * 16 + lg * 4] = pk;
    }
  }
}

// ---------------- GEMM4: ctx[8192][1024] x Wot[1024][1024] -> out fp32 ----------------
__global__ __launch_bounds__(256, 2) void k_gemm_out(
    const unsigned short* __restrict__ A,
    const unsigned short* __restrict__ Bt,
    float* __restrict__ C) {
  constexpr int K = 1024;
  __shared__ __align__(16) unsigned short As[128 * 32];
  __shared__ __align__(16) unsigned short Bs[128 * 32];
  const int tid = threadIdx.x;
  const int l = tid & 63, w = tid >> 6;
  const int lr = l & 15, lg = l >> 4;
  const int bm = blockIdx.x, bn = blockIdx.y;
  const int wr = (w >> 1) * 64, wc = (w & 1) * 64;

  f32x4 acc[4][4] = {};

  const int o0 = tid * 16, o1 = tid * 16 + 4096;
  const int r0 = o0 >> 6, c0 = o0 & 63;
  const int r1 = o1 >> 6, c1 = o1 & 63;
  const char* gA0 = (const char*)A + (size_t)(bm * 128 + r0) * (K * 2) + c0;
  const char* gA1 = (const char*)A + (size_t)(bm * 128 + r1) * (K * 2) + c1;
  const char* gB0 = (const char*)Bt + (size_t)(bn * 128 + r0) * (K * 2) + c0;
  const char* gB1 = (const char*)Bt + (size_t)(bn * 128 + r1) * (K * 2) + c1;
  char* lA0 = (char*)As + o0;
  char* lA1 = (char*)As + o1;
  char* lB0 = (char*)Bs + o0;
  char* lB1 = (char*)Bs + o1;

  for (int kt = 0; kt < K / 32; ++kt) {
    const int kb = kt * 64;
    gload_lds16(gA0 + kb, lA0);
    gload_lds16(gA1 + kb, lA1);
    gload_lds16(gB0 + kb, lB0);
    gload_lds16(gB1 + kb, lB1);
    __syncthreads();
    bf16x8 af[4], bfr[4];
#pragma unroll
    for (int mf = 0; mf < 4; ++mf)
      af[mf] = *(const bf16x8*)&As[(wr + mf * 16 + lr) * 32 + lg * 8];
#pragma unroll
    for (int nf = 0; nf < 4; ++nf)
      bfr[nf] = *(const bf16x8*)&Bs[(wc + nf * 16 + lr) * 32 + lg * 8];
#pragma unroll
    for (int mf = 0; mf < 4; ++mf)
#pragma unroll
      for (int nf = 0; nf < 4; ++nf)
        acc[mf][nf] = MFMA16(af[mf], bfr[nf], acc[mf][nf]);
    __syncthreads();
  }

#pragma unroll
  for (int mf = 0; mf < 4; ++mf)
#pragma unroll
    for (int i = 0; i < 4; ++i) {
      const int r = bm * 128 + wr + mf * 16 + lg * 4 + i;
#pragma unroll
      for (int nf = 0; nf < 4; ++nf)
        C[(size_t)r * 1024 + bn * 128 + wc + nf * 16 + lr] = acc[mf][nf][i];
    }
}

// ---------------- host launch ----------------
extern "C" void kernel_launch(void* const* d_in, const int* in_sizes, int n_in,
                              void* d_out, int out_size, void* d_ws, size_t ws_size,
                              hipStream_t stream) {
  const float* X = (const float*)d_in[0];    // (2048,4,1024)
  const float* W1 = (const float*)d_in[1];   // (3072,1024)
  const float* Wo = (const float*)d_in[2];   // (1024,1024)
  float* out = (float*)d_out;                // (2048,4,1024) fp32

  char* ws = (char*)d_ws;
  unsigned short* Xb  = (unsigned short*)(ws);              // 16 MB
  unsigned short* W1b = (unsigned short*)(ws + 16777216);   //  6 MB
  unsigned short* Wob = (unsigned short*)(ws + 23068672);   //  2 MB
  unsigned short* Qb  = (unsigned short*)(ws + 25165824);   // 16 MB
  unsigned short* Kb  = (unsigned short*)(ws + 41943040);   // 16 MB
  unsigned short* VTb = (unsigned short*)(ws + 58720256);   // 16 MB
  // Vb aliases the Cx slot: Vb is dead after k_vtrans, Cx written only by k_attn (later).
  unsigned short* Vb  = (unsigned short*)(ws + 75497472);   // 16 MB
  unsigned short* Cx  = (unsigned short*)(ws + 75497472);   // same 16 MB

  k_cvt<<<8192, 256, 0, stream>>>(X, Xb, 2097152);
  k_cvt<<<3072, 256, 0, stream>>>(W1, W1b, 786432);
  k_cvt<<<1024, 256, 0, stream>>>(Wo, Wob, 262144);
  k_gemm_qkv<<<dim3(32, 12), 512, 0, stream>>>(Xb, W1b, Qb, Kb, Vb);
  k_vtrans<<<dim3(32, 64), 256, 0, stream>>>(Vb, VTb);
  k_attn<<<dim3(64, 8), 256, 0, stream>>>(Qb, Kb, VTb, Cx);
  k_gemm_out<<<dim3(64, 8), 256, 0, stream>>>(Cx, Wob, out);
}